// Round 2
// baseline (66.876 us; speedup 1.0000x reference)
//
#include <hip/hip_runtime.h>

#define DIMQ 4096   // 2^12
#define NPAIR 6     // six 2-qubit pair gates
#define DA 64       // 2^dimA, dimA = 6

__device__ __forceinline__ float2 cmul(float2 a, float2 b) {
    return make_float2(a.x*b.x - a.y*b.y, a.x*b.y + a.y*b.x);
}

// Grid: B*4 blocks, 1024 threads. Block (b, s) recomputes phi = U psi_b in LDS
// (cheap), then emits rows [s*16, s*16+16) of the 64x64 reduced density matrix.
// real_only: harness coerced the complex64 reference to float32 real parts
// (out_size==8192) vs interleaved view (out_size==16384).
__global__ __launch_bounds__(1024) void quconv_kernel(
    const float* __restrict__ x,      // [B, 1, 4096] fp32 (real states)
    const float* __restrict__ w,      // [72] fp32 weights
    float* __restrict__ out,          // see real_only
    int real_only)
{
    __shared__ float2 buf[DIMQ];      // the state vector (32 KB)
    __shared__ float2 G[NPAIR][16];   // six 4x4 complex pair gates

    const int tid = threadIdx.x;
    const int b   = blockIdx.x >> 2;  // batch index
    const int s   = blockIdx.x & 3;   // row-slice index (16 rows each)

    // ---- build pair gates: thread p computes G[p] = Rzz @ Ryy @ Rxx ----
    if (tid < NPAIR) {
        const float WM = 0.63245553203367586640f;  // sqrt(2)/sqrt(5)
        const int base = 36 + 6 * tid;             // idx = 3n + 3*(2p)
        const float tx = 0.5f * WM * w[base + 0];
        const float ty = 0.5f * WM * w[base + 1];
        const float tz = 0.5f * WM * w[base + 2];
        const float cx = cosf(tx), sx = sinf(tx);
        const float cy = cosf(ty), sy = sinf(ty);
        const float cz = cosf(tz), sz = sinf(tz);

        float2 Rxx[16], Ryy[16], A[16];
        for (int k = 0; k < 16; ++k) { Rxx[k] = make_float2(0,0); Ryy[k] = make_float2(0,0); }
        // Rxx = cx*I - i*sx*XX  (XX = antidiagonal ones)
        for (int j = 0; j < 4; ++j) {
            Rxx[j*4 + j]     = make_float2(cx, 0.f);
            Rxx[j*4 + (3-j)] = make_float2(0.f, -sx);
        }
        // Ryy = cy*I - i*sy*YY,  YY = [[0,0,0,-1],[0,0,1,0],[0,1,0,0],[-1,0,0,0]]
        Ryy[0] = Ryy[5] = Ryy[10] = Ryy[15] = make_float2(cy, 0.f);
        Ryy[3]  = make_float2(0.f,  sy);
        Ryy[6]  = make_float2(0.f, -sy);
        Ryy[9]  = make_float2(0.f, -sy);
        Ryy[12] = make_float2(0.f,  sy);
        // A = Ryy @ Rxx
        for (int i = 0; i < 4; ++i)
            for (int j = 0; j < 4; ++j) {
                float2 acc = make_float2(0.f, 0.f);
                for (int k = 0; k < 4; ++k) {
                    float2 t = cmul(Ryy[i*4 + k], Rxx[k*4 + j]);
                    acc.x += t.x; acc.y += t.y;
                }
                A[i*4 + j] = acc;
            }
        // Rzz = diag(e^-it, e^+it, e^+it, e^-it), t = tz  -> G = Rzz @ A (row scale)
        const float2 rz[4] = { make_float2(cz, -sz), make_float2(cz,  sz),
                               make_float2(cz,  sz), make_float2(cz, -sz) };
        for (int i = 0; i < 4; ++i)
            for (int j = 0; j < 4; ++j)
                G[tid][i*4 + j] = cmul(rz[i], A[i*4 + j]);
    }

    // ---- load psi_b (real -> complex) ----
    for (int idx = tid; idx < DIMQ; idx += 1024)
        buf[idx] = make_float2(x[b * DIMQ + idx], 0.f);

    // ---- apply the 6 pair gates in place ----
    // Index = sum_p digit_p * 4^(5-p); gate p acts on digit p (shift = 2*(5-p)).
    // Each 4-group is owned by exactly one thread -> in-place is race-free.
    for (int p = 0; p < NPAIR; ++p) {
        __syncthreads();
        const int shift = 2 * (5 - p);
        const int g = tid;                          // 1024 groups, 1024 threads
        const int low  = g & ((1 << shift) - 1);
        const int base = ((g >> shift) << (shift + 2)) | low;
        const float2 v0 = buf[base];
        const float2 v1 = buf[base + (1 << shift)];
        const float2 v2 = buf[base + (2 << shift)];
        const float2 v3 = buf[base + (3 << shift)];
        #pragma unroll
        for (int j = 0; j < 4; ++j) {
            float2 acc = cmul(G[p][j*4 + 0], v0);
            float2 t1  = cmul(G[p][j*4 + 1], v1); acc.x += t1.x; acc.y += t1.y;
            float2 t2  = cmul(G[p][j*4 + 2], v2); acc.x += t2.x; acc.y += t2.y;
            float2 t3  = cmul(G[p][j*4 + 3], v3); acc.x += t3.x; acc.y += t3.y;
            buf[base + (j << shift)] = acc;
        }
    }
    __syncthreads();

    // ---- reduced density matrix over leading 6 qubits ----
    // red[i,j] = sum_t phi[t*64+i] * conj(phi[t*64+j])
    const int i = (s << 4) + (tid >> 6);   // rows s*16 .. s*16+15
    const int j = tid & 63;
    float re = 0.f, im = 0.f;
    #pragma unroll 8
    for (int t = 0; t < 64; ++t) {
        const float2 pi = buf[t * DA + i];
        const float2 pj = buf[t * DA + j];
        re += pi.x * pj.x + pi.y * pj.y;
        im += pi.y * pj.x - pi.x * pj.y;
    }
    const int e = b * (DA * DA) + i * DA + j;
    if (real_only) {
        out[e] = re;                       // complex64 ref coerced via astype -> real part
    } else {
        ((float2*)out)[e] = make_float2(re, im);   // complex64 viewed as interleaved f32
    }
}

extern "C" void kernel_launch(void* const* d_in, const int* in_sizes, int n_in,
                              void* d_out, int out_size, void* d_ws, size_t ws_size,
                              hipStream_t stream) {
    const float* x = (const float*)d_in[0];   // [2,1,4096] fp32
    const float* w = (const float*)d_in[1];   // [72] fp32
    const int B = in_sizes[0] / DIMQ;         // = 2
    const int real_only = (out_size == B * DA * DA) ? 1 : 0;  // 8192 -> real part only
    quconv_kernel<<<dim3(B * 4), dim3(1024), 0, stream>>>(x, w, (float*)d_out, real_only);
}

// Round 3
// 62.954 us; speedup vs baseline: 1.0623x; 1.0623x over previous
//
#include <hip/hip_runtime.h>

#define DIMQ 4096   // 2^12
#define NPAIR 6     // six 2-qubit pair gates
#define DA 64       // 2^dimA, dimA = 6

__device__ __forceinline__ float2 cmul(float2 a, float2 b) {
    return make_float2(a.x*b.x - a.y*b.y, a.x*b.y + a.y*b.x);
}
__device__ __forceinline__ float2 cfma2(float2 a, float2 u, float2 b, float2 v) {
    // a*u + b*v (complex)
    return make_float2(a.x*u.x - a.y*u.y + b.x*v.x - b.y*v.y,
                       a.x*u.y + a.y*u.x + b.x*v.y + b.y*v.x);
}

// Grid: B*4 blocks, 1024 threads. Block (b, s) recomputes phi = U psi_b in LDS,
// then emits rows [s*16, s*16+16) of the 64x64 reduced density matrix.
//
// Pair gate closed form (x,y,z = half-angles of rxx,ryy,rzz):
//   on {00,11}: e^{-iz} * [[cos(x-y), -i sin(x-y)], [-i sin(x-y), cos(x-y)]]
//   on {01,10}: e^{+iz} * [[cos(x+y), -i sin(x+y)], [-i sin(x+y), cos(x+y)]]
// -> 4 complex constants per gate: A, B (00/11 block), C, D (01/10 block).
__global__ __launch_bounds__(1024) void quconv_kernel(
    const float* __restrict__ x,      // [B, 1, 4096] fp32 (real states)
    const float* __restrict__ w,      // [72] fp32 weights
    float* __restrict__ out,          // complex64 out, layout per real_only
    int real_only)
{
    __shared__ float2 buf[DIMQ];      // the state vector (32 KB)
    __shared__ float2 G[NPAIR][4];    // {A, B, C, D} per gate

    const int tid = threadIdx.x;
    const int b   = blockIdx.x >> 2;  // batch index
    const int s   = blockIdx.x & 3;   // row-slice index (16 rows each)

    // ---- build pair gates: thread p computes gate p's 4 constants ----
    if (tid < NPAIR) {
        const float WM = 0.63245553203367586640f;  // sqrt(2)/sqrt(5)
        const int base = 36 + 6 * tid;             // idx = 3n + 3*(2p)
        const float tx = 0.5f * WM * w[base + 0];
        const float ty = 0.5f * WM * w[base + 1];
        const float tz = 0.5f * WM * w[base + 2];
        float cm, sm, cp, sp, cz, sz;
        __sincosf(tx - ty, &sm, &cm);
        __sincosf(tx + ty, &sp, &cp);
        __sincosf(tz,      &sz, &cz);
        const float2 em = make_float2(cz, -sz);   // e^{-iz}
        const float2 ep = make_float2(cz,  sz);   // e^{+iz}
        G[tid][0] = make_float2(cz * cm, -sz * cm);            // A = e^{-iz} cos(x-y)
        G[tid][1] = cmul(em, make_float2(0.f, -sm));           // B = -i e^{-iz} sin(x-y)
        G[tid][2] = make_float2(cz * cp,  sz * cp);            // C = e^{+iz} cos(x+y)
        G[tid][3] = cmul(ep, make_float2(0.f, -sp));           // D = -i e^{+iz} sin(x+y)
    }

    // ---- load psi_b (real -> complex), float4-vectorized ----
    {
        const float4 v = ((const float4*)(x + b * DIMQ))[tid];
        buf[tid * 4 + 0] = make_float2(v.x, 0.f);
        buf[tid * 4 + 1] = make_float2(v.y, 0.f);
        buf[tid * 4 + 2] = make_float2(v.z, 0.f);
        buf[tid * 4 + 3] = make_float2(v.w, 0.f);
    }

    // ---- apply the 6 pair gates in place (sparse: 2 nonzeros/row) ----
    // Index = sum_p digit_p * 4^(5-p); gate p acts on digit p (shift = 2*(5-p)).
    for (int p = 0; p < NPAIR; ++p) {
        __syncthreads();
        const int shift = 2 * (5 - p);
        const int g = tid;                          // 1024 groups, 1024 threads
        const int low  = g & ((1 << shift) - 1);
        const int base = ((g >> shift) << (shift + 2)) | low;
        const int s1 = 1 << shift;
        const float2 A = G[p][0], B = G[p][1], C = G[p][2], D = G[p][3];
        const float2 v0 = buf[base];
        const float2 v1 = buf[base + s1];
        const float2 v2 = buf[base + 2 * s1];
        const float2 v3 = buf[base + 3 * s1];
        buf[base]          = cfma2(A, v0, B, v3);
        buf[base + s1]     = cfma2(C, v1, D, v2);
        buf[base + 2 * s1] = cfma2(D, v1, C, v2);
        buf[base + 3 * s1] = cfma2(B, v0, A, v3);
    }
    __syncthreads();

    // ---- reduced density matrix over leading 6 qubits ----
    // red[i,j] = sum_t phi[t*64+i] * conj(phi[t*64+j])
    const int i = (s << 4) + (tid >> 6);   // rows s*16 .. s*16+15
    const int j = tid & 63;
    float re = 0.f, im = 0.f;
    #pragma unroll 8
    for (int t = 0; t < 64; ++t) {
        const float2 pi = buf[t * DA + i];
        const float2 pj = buf[t * DA + j];
        re += pi.x * pj.x + pi.y * pj.y;
        im += pi.y * pj.x - pi.x * pj.y;
    }
    const int e = b * (DA * DA) + i * DA + j;
    if (real_only) {
        out[e] = re;                       // complex64 ref coerced to real part
    } else {
        ((float2*)out)[e] = make_float2(re, im);   // interleaved complex64
    }
}

extern "C" void kernel_launch(void* const* d_in, const int* in_sizes, int n_in,
                              void* d_out, int out_size, void* d_ws, size_t ws_size,
                              hipStream_t stream) {
    const float* x = (const float*)d_in[0];   // [2,1,4096] fp32
    const float* w = (const float*)d_in[1];   // [72] fp32
    const int B = in_sizes[0] / DIMQ;         // = 2
    const int real_only = (out_size == B * DA * DA) ? 1 : 0;  // 8192 -> real-only
    quconv_kernel<<<dim3(B * 4), dim3(1024), 0, stream>>>(x, w, (float*)d_out, real_only);
}

// Round 4
// 62.412 us; speedup vs baseline: 1.0715x; 1.0087x over previous
//
#include <hip/hip_runtime.h>

#define DIMQ 4096   // 2^12
#define NPAIR 6     // six 2-qubit pair gates
#define DA 64       // 2^dimA, dimA = 6

__device__ __forceinline__ float2 cmul(float2 a, float2 b) {
    return make_float2(a.x*b.x - a.y*b.y, a.x*b.y + a.y*b.x);
}
__device__ __forceinline__ float2 cfma2(float2 a, float2 u, float2 b, float2 v) {
    // a*u + b*v (complex)
    return make_float2(a.x*u.x - a.y*u.y + b.x*v.x - b.y*v.y,
                       a.x*u.y + a.y*u.x + b.x*v.y + b.y*v.x);
}

// Grid: B*16 blocks, 1024 threads. Block (b, s) recomputes phi = U psi_b in LDS
// (redundant across blocks but parallel across CUs), then emits rows
// [s*4, s*4+4) of the 64x64 reduced density matrix; each (i,j) is summed by
// 4 threads over 16 t-values each, combined via shfl_xor.
//
// Pair gate closed form (x,y,z = half-angles of rxx,ryy,rzz):
//   on {00,11}: e^{-iz} * [[cos(x-y), -i sin(x-y)], [-i sin(x-y), cos(x-y)]]
//   on {01,10}: e^{+iz} * [[cos(x+y), -i sin(x+y)], [-i sin(x+y), cos(x+y)]]
// -> 4 complex constants per gate: A, B (00/11 block), C, D (01/10 block).
__global__ __launch_bounds__(1024) void quconv_kernel(
    const float* __restrict__ x,      // [B, 1, 4096] fp32 (real states)
    const float* __restrict__ w,      // [72] fp32 weights
    float* __restrict__ out,          // complex64 out, layout per real_only
    int real_only)
{
    __shared__ float2 buf[DIMQ];      // the state vector (32 KB)
    __shared__ float2 G[NPAIR][4];    // {A, B, C, D} per gate

    const int tid = threadIdx.x;
    const int b   = blockIdx.x >> 4;  // batch index
    const int s   = blockIdx.x & 15;  // row-slice index (4 rows each)

    // ---- build pair gates: thread p computes gate p's 4 constants ----
    if (tid < NPAIR) {
        const float WM = 0.63245553203367586640f;  // sqrt(2)/sqrt(5)
        const int base = 36 + 6 * tid;             // idx = 3n + 3*(2p)
        const float tx = 0.5f * WM * w[base + 0];
        const float ty = 0.5f * WM * w[base + 1];
        const float tz = 0.5f * WM * w[base + 2];
        float cm, sm, cp, sp, cz, sz;
        __sincosf(tx - ty, &sm, &cm);
        __sincosf(tx + ty, &sp, &cp);
        __sincosf(tz,      &sz, &cz);
        const float2 em = make_float2(cz, -sz);   // e^{-iz}
        const float2 ep = make_float2(cz,  sz);   // e^{+iz}
        G[tid][0] = make_float2(cz * cm, -sz * cm);            // A = e^{-iz} cos(x-y)
        G[tid][1] = cmul(em, make_float2(0.f, -sm));           // B = -i e^{-iz} sin(x-y)
        G[tid][2] = make_float2(cz * cp,  sz * cp);            // C = e^{+iz} cos(x+y)
        G[tid][3] = cmul(ep, make_float2(0.f, -sp));           // D = -i e^{+iz} sin(x+y)
    }

    // ---- load psi_b for gate-pass 0 (shift=10): group g=tid owns elements
    //      {tid, tid+1024, tid+2048, tid+3072}; coalesced dword loads ----
    const float r0 = x[b * DIMQ + tid];
    const float r1 = x[b * DIMQ + tid + 1024];
    const float r2 = x[b * DIMQ + tid + 2048];
    const float r3 = x[b * DIMQ + tid + 3072];

    __syncthreads();   // gates ready

    // ---- pass 0 in registers (inputs real -> 2 mults per output) ----
    {
        const float2 A = G[0][0], B = G[0][1], C = G[0][2], D = G[0][3];
        buf[tid]        = make_float2(A.x*r0 + B.x*r3, A.y*r0 + B.y*r3);
        buf[tid + 1024] = make_float2(C.x*r1 + D.x*r2, C.y*r1 + D.y*r2);
        buf[tid + 2048] = make_float2(D.x*r1 + C.x*r2, D.y*r1 + C.y*r2);
        buf[tid + 3072] = make_float2(B.x*r0 + A.x*r3, B.y*r0 + A.y*r3);
    }

    // ---- passes 1..5 in place (sparse: 2 nonzeros/row) ----
    for (int p = 1; p < NPAIR; ++p) {
        __syncthreads();
        const int shift = 2 * (5 - p);
        const int g = tid;                          // 1024 groups, 1024 threads
        const int low  = g & ((1 << shift) - 1);
        const int base = ((g >> shift) << (shift + 2)) | low;
        const int s1 = 1 << shift;
        const float2 A = G[p][0], B = G[p][1], C = G[p][2], D = G[p][3];
        const float2 v0 = buf[base];
        const float2 v1 = buf[base + s1];
        const float2 v2 = buf[base + 2 * s1];
        const float2 v3 = buf[base + 3 * s1];
        buf[base]          = cfma2(A, v0, B, v3);
        buf[base + s1]     = cfma2(C, v1, D, v2);
        buf[base + 2 * s1] = cfma2(D, v1, C, v2);
        buf[base + 3 * s1] = cfma2(B, v0, A, v3);
    }
    __syncthreads();

    // ---- reduced density matrix over leading 6 qubits ----
    // red[i,j] = sum_t phi[t*64+i] * conj(phi[t*64+j])
    // thread -> (i, j, t-chunk): c = tid&3 (16 t's each), j = (tid>>2)&63,
    // i = s*4 + (tid>>8). Lanes c=0..3 of each j-group combine via shfl_xor.
    const int c = tid & 3;
    const int j = (tid >> 2) & 63;
    const int i = (s << 2) + (tid >> 8);
    float re = 0.f, im = 0.f;
    const int t0 = c << 4;
    #pragma unroll
    for (int t = t0; t < t0 + 16; ++t) {
        const float2 pi = buf[t * DA + i];
        const float2 pj = buf[t * DA + j];
        re += pi.x * pj.x + pi.y * pj.y;
        im += pi.y * pj.x - pi.x * pj.y;
    }
    re += __shfl_xor(re, 1); im += __shfl_xor(im, 1);
    re += __shfl_xor(re, 2); im += __shfl_xor(im, 2);
    if (c == 0) {
        const int e = b * (DA * DA) + i * DA + j;
        if (real_only) {
            out[e] = re;                             // complex64 ref coerced to real part
        } else {
            ((float2*)out)[e] = make_float2(re, im); // interleaved complex64
        }
    }
}

extern "C" void kernel_launch(void* const* d_in, const int* in_sizes, int n_in,
                              void* d_out, int out_size, void* d_ws, size_t ws_size,
                              hipStream_t stream) {
    const float* x = (const float*)d_in[0];   // [2,1,4096] fp32
    const float* w = (const float*)d_in[1];   // [72] fp32
    const int B = in_sizes[0] / DIMQ;         // = 2
    const int real_only = (out_size == B * DA * DA) ? 1 : 0;  // 8192 -> real-only
    quconv_kernel<<<dim3(B * 16), dim3(1024), 0, stream>>>(x, w, (float*)d_out, real_only);
}

// Round 5
// 60.645 us; speedup vs baseline: 1.1028x; 1.0291x over previous
//
#include <hip/hip_runtime.h>

#define DIMQ 4096   // 2^12
#define NPAIR 6     // six 2-qubit pair gates
#define DA 64       // 2^dimA, dimA = 6

// Padded LDS addressing: stride-65 float2 rows (64 elems + 1 pad) so that
// column-parallel reads in the reduction hit different banks (row stride
// 512 B === 0 mod 128 B would put a whole column in one bank otherwise).
#define PAD(i) ((i) + ((i) >> 6))

__device__ __forceinline__ float2 cmul(float2 a, float2 b) {
    return make_float2(a.x*b.x - a.y*b.y, a.x*b.y + a.y*b.x);
}
__device__ __forceinline__ float2 cfma2(float2 a, float2 u, float2 b, float2 v) {
    // a*u + b*v (complex)
    return make_float2(a.x*u.x - a.y*u.y + b.x*v.x - b.y*v.y,
                       a.x*u.y + a.y*u.x + b.x*v.y + b.y*v.x);
}

// Grid: B*64 blocks, 1024 threads. Block (b, i) recomputes phi = U psi_b in
// LDS (redundant across blocks but parallel across 256 CUs), then emits row i
// of the 64x64 reduced density matrix. Each (i,j): 16 threads x 4 t-values,
// combined via shfl_xor over the 16-lane group.
//
// Pair gate closed form (x,y,z = half-angles of rxx,ryy,rzz):
//   on {00,11}: e^{-iz} * [[cos(x-y), -i sin(x-y)], [-i sin(x-y), cos(x-y)]]
//   on {01,10}: e^{+iz} * [[cos(x+y), -i sin(x+y)], [-i sin(x+y), cos(x+y)]]
__global__ __launch_bounds__(1024) void quconv_kernel(
    const float* __restrict__ x,      // [B, 1, 4096] fp32 (real states)
    const float* __restrict__ w,      // [72] fp32 weights
    float* __restrict__ out,          // complex64 out, layout per real_only
    int real_only)
{
    __shared__ float2 buf[DIMQ + DIMQ / 64];  // padded state (32.5 KB)
    __shared__ float2 G[NPAIR][4];            // {A, B, C, D} per gate

    const int tid = threadIdx.x;
    const int b   = blockIdx.x >> 6;  // batch index
    const int i   = blockIdx.x & 63;  // output row of this block

    // ---- build pair gates: thread p computes gate p's 4 constants ----
    if (tid < NPAIR) {
        const float WM = 0.63245553203367586640f;  // sqrt(2)/sqrt(5)
        const int base = 36 + 6 * tid;             // idx = 3n + 3*(2p)
        const float tx = 0.5f * WM * w[base + 0];
        const float ty = 0.5f * WM * w[base + 1];
        const float tz = 0.5f * WM * w[base + 2];
        float cm, sm, cp, sp, cz, sz;
        __sincosf(tx - ty, &sm, &cm);
        __sincosf(tx + ty, &sp, &cp);
        __sincosf(tz,      &sz, &cz);
        const float2 em = make_float2(cz, -sz);   // e^{-iz}
        const float2 ep = make_float2(cz,  sz);   // e^{+iz}
        G[tid][0] = make_float2(cz * cm, -sz * cm);            // A = e^{-iz} cos(x-y)
        G[tid][1] = cmul(em, make_float2(0.f, -sm));           // B = -i e^{-iz} sin(x-y)
        G[tid][2] = make_float2(cz * cp,  sz * cp);            // C = e^{+iz} cos(x+y)
        G[tid][3] = cmul(ep, make_float2(0.f, -sp));           // D = -i e^{+iz} sin(x+y)
    }

    // ---- load psi_b for gate-pass 0 (shift=10): group g=tid owns elements
    //      {tid, tid+1024, tid+2048, tid+3072}; coalesced dword loads ----
    const float r0 = x[b * DIMQ + tid];
    const float r1 = x[b * DIMQ + tid + 1024];
    const float r2 = x[b * DIMQ + tid + 2048];
    const float r3 = x[b * DIMQ + tid + 3072];

    __syncthreads();   // gates ready

    // ---- pass 0 in registers (inputs real -> 2 mults per output) ----
    {
        const float2 A = G[0][0], B = G[0][1], C = G[0][2], D = G[0][3];
        buf[PAD(tid)]        = make_float2(A.x*r0 + B.x*r3, A.y*r0 + B.y*r3);
        buf[PAD(tid + 1024)] = make_float2(C.x*r1 + D.x*r2, C.y*r1 + D.y*r2);
        buf[PAD(tid + 2048)] = make_float2(D.x*r1 + C.x*r2, D.y*r1 + C.y*r2);
        buf[PAD(tid + 3072)] = make_float2(B.x*r0 + A.x*r3, B.y*r0 + A.y*r3);
    }

    // ---- passes 1..5 in place (sparse: 2 nonzeros/row) ----
    for (int p = 1; p < NPAIR; ++p) {
        __syncthreads();
        const int shift = 2 * (5 - p);
        const int g = tid;                          // 1024 groups, 1024 threads
        const int low  = g & ((1 << shift) - 1);
        const int base = ((g >> shift) << (shift + 2)) | low;
        const int s1 = 1 << shift;
        const int e0 = PAD(base);
        const int e1 = PAD(base + s1);
        const int e2 = PAD(base + 2 * s1);
        const int e3 = PAD(base + 3 * s1);
        const float2 A = G[p][0], B = G[p][1], C = G[p][2], D = G[p][3];
        const float2 v0 = buf[e0];
        const float2 v1 = buf[e1];
        const float2 v2 = buf[e2];
        const float2 v3 = buf[e3];
        buf[e0] = cfma2(A, v0, B, v3);
        buf[e1] = cfma2(C, v1, D, v2);
        buf[e2] = cfma2(D, v1, C, v2);
        buf[e3] = cfma2(B, v0, A, v3);
    }
    __syncthreads();

    // ---- row i of the reduced density matrix ----
    // red[i,j] = sum_t phi[t*64+i] * conj(phi[t*64+j])
    // thread -> (j, t-chunk): c = tid&15 (4 t's each), j = tid>>4.
    // Lanes c=0..15 of each j-group (contiguous within a wave) shfl-reduce.
    const int c = tid & 15;
    const int j = tid >> 4;
    float re = 0.f, im = 0.f;
    #pragma unroll
    for (int k = 0; k < 4; ++k) {
        const int t = (c << 2) + k;
        const float2 pi = buf[t * (DA + 1) + i];   // PAD(t*64+i) = t*65+i
        const float2 pj = buf[t * (DA + 1) + j];
        re += pi.x * pj.x + pi.y * pj.y;
        im += pi.y * pj.x - pi.x * pj.y;
    }
    re += __shfl_xor(re, 1); im += __shfl_xor(im, 1);
    re += __shfl_xor(re, 2); im += __shfl_xor(im, 2);
    re += __shfl_xor(re, 4); im += __shfl_xor(im, 4);
    re += __shfl_xor(re, 8); im += __shfl_xor(im, 8);
    if (c == 0) {
        const int e = b * (DA * DA) + i * DA + j;
        if (real_only) {
            out[e] = re;                             // complex64 ref coerced to real part
        } else {
            ((float2*)out)[e] = make_float2(re, im); // interleaved complex64
        }
    }
}

extern "C" void kernel_launch(void* const* d_in, const int* in_sizes, int n_in,
                              void* d_out, int out_size, void* d_ws, size_t ws_size,
                              hipStream_t stream) {
    const float* x = (const float*)d_in[0];   // [2,1,4096] fp32
    const float* w = (const float*)d_in[1];   // [72] fp32
    const int B = in_sizes[0] / DIMQ;         // = 2
    const int real_only = (out_size == B * DA * DA) ? 1 : 0;  // 8192 -> real-only
    quconv_kernel<<<dim3(B * 64), dim3(1024), 0, stream>>>(x, w, (float*)d_out, real_only);
}

// Round 6
// 58.744 us; speedup vs baseline: 1.1384x; 1.0324x over previous
//
#include <hip/hip_runtime.h>

#define DIMQ 4096   // 2^12
#define DA 64       // 2^dimA
#define LST 66      // padded LDS row stride for Xt (floats): 66 ≡ 2 mod 32 banks

__device__ __forceinline__ float2 cmul(float2 a, float2 b) {
    return make_float2(a.x*b.x - a.y*b.y, a.x*b.y + a.y*b.x);
}
__device__ __forceinline__ float2 conjf2(float2 a) { return make_float2(a.x, -a.y); }

// Algebraic form: red = G_A * (X^T X) * G_A^dagger, where X = reshape(x, 64x64)
// (real) and G_A = g3 (x) g4 (x) g5 acts on the kept 6 qubits. Gates 0-2 act only
// on the traced-out subsystem and drop out (G_B^dagger G_B = I under the t-sum).
//
// Pair gate closed form (x,y,z = half-angles): on digit values {0,3}:
// [[A,B],[B,A]]; on {1,2}: [[C,D],[D,C]], with A=e^{-iz}cos(x-y),
// B=-i e^{-iz}sin(x-y), C=e^{+iz}cos(x+y), D=-i e^{+iz}sin(x+y).
// Each gate only mixes digit d <-> 3-d, so the 64 rows split into 8 orbits of 8.
//
// Grid: B*8 blocks x 512 threads. Block (b, o) owns row-orbit o; thread
// (m = tid>>6, j = tid&63) computes red[r(o,m), j]:
//   1. stage X transposed in LDS (Xt[i][t], padded stride 66)
//   2. gram: v = sum_t Xt[r][t]*Xt[j][t]   (row-r read is a wave broadcast)
//   3. column gating (M G_A^dagger): 3 passes of __shfl_xor (masks 48/12/3)
//   4. row gating (G_A *): one LDS exchange + 8-term orbit sum
__global__ __launch_bounds__(512) void quconv_kernel(
    const float* __restrict__ x,      // [B, 1, 4096] fp32 (real states)
    const float* __restrict__ w,      // [72] fp32 weights
    float* __restrict__ out,          // complex64 out, layout per real_only
    int real_only)
{
    __shared__ float  Xt[DA][LST];    // X transposed: Xt[i][t]  (16.9 KB)
    __shared__ float2 exch[8][DA + 1];// orbit row-exchange (4.2 KB)
    __shared__ float2 G[3][4];        // gate for digit k: {A, B, C, D}

    const int tid = threadIdx.x;
    const int b   = blockIdx.x >> 3;  // batch index
    const int o   = blockIdx.x & 7;   // row orbit

    // ---- gates for digits k=2,1,0 (circuit gates p=3,4,5; w-base 54+6*(2-k)) ----
    if (tid < 3) {
        const int k = tid;
        const float WM = 0.63245553203367586640f;  // sqrt(2)/sqrt(5)
        const int base = 54 + 6 * (2 - k);
        const float tx = 0.5f * WM * w[base + 0];
        const float ty = 0.5f * WM * w[base + 1];
        const float tz = 0.5f * WM * w[base + 2];
        float cm, sm, cp, sp, cz, sz;
        __sincosf(tx - ty, &sm, &cm);
        __sincosf(tx + ty, &sp, &cp);
        __sincosf(tz,      &sz, &cz);
        G[k][0] = make_float2(cz * cm, -sz * cm);                    // A
        G[k][1] = cmul(make_float2(cz, -sz), make_float2(0.f, -sm)); // B
        G[k][2] = make_float2(cz * cp,  sz * cp);                    // C
        G[k][3] = cmul(make_float2(cz,  sz), make_float2(0.f, -sp)); // D
    }

    const int m = tid >> 6;           // orbit member 0..7
    const int j = tid & 63;           // column

    // ---- stage X transposed: thread (m,j) loads t = m*8+q, col j (coalesced) ----
    {
        float v[8];
        #pragma unroll
        for (int q = 0; q < 8; ++q)
            v[q] = x[b * DIMQ + (m * 8 + q) * DA + j];
        #pragma unroll
        for (int q = 0; q < 8; q += 2)
            *(float2*)&Xt[j][m * 8 + q] = make_float2(v[q], v[q + 1]);
    }
    __syncthreads();

    // ---- this thread's output row r(o, m): digit k = b_k? (m_k? 2:1) : (m_k? 3:0) ----
    int r = 0;
    #pragma unroll
    for (int k = 0; k < 3; ++k) {
        const int bk = (o >> k) & 1;
        const int mk = (m >> k) & 1;
        const int d  = bk ? (mk ? 2 : 1) : (mk ? 3 : 0);
        r += d << (2 * k);
    }

    // ---- gram: v = sum_t X[t,r] X[t,j]  (real) ----
    float acc = 0.f;
    {
        const float* xr = Xt[r];      // wave-uniform -> LDS broadcast reads
        const float* xj = Xt[j];
        #pragma unroll
        for (int t = 0; t < DA; t += 2) {
            const float2 a = *(const float2*)&xr[t];
            const float2 c = *(const float2*)&xj[t];
            acc += a.x * c.x + a.y * c.y;
        }
    }
    float2 v = make_float2(acc, 0.f);

    // ---- column gating: v <- (M G_A^dagger) entries, 3 in-wave passes ----
    #pragma unroll
    for (int k = 2; k >= 0; --k) {
        const int mask = 3 << (2 * k);            // 48, 12, 3
        const int d    = (j >> (2 * k)) & 3;
        const bool mid = (d == 1) || (d == 2);
        const float2 P = conjf2(mid ? G[k][2] : G[k][0]);
        const float2 Q = conjf2(mid ? G[k][3] : G[k][1]);
        const float2 vp = make_float2(__shfl_xor(v.x, mask), __shfl_xor(v.y, mask));
        const float2 t1 = cmul(P, v);
        const float2 t2 = cmul(Q, vp);
        v = make_float2(t1.x + t2.x, t1.y + t2.y);
    }

    // ---- row gating: red[r(m),j] = sum_{m'} [prod_k (flip? off_k : diag_k)] * N[r(m'),j] ----
    exch[m][j] = v;
    __syncthreads();
    float2 res = make_float2(0.f, 0.f);
    #pragma unroll
    for (int mp = 0; mp < 8; ++mp) {
        float2 cf = make_float2(1.f, 0.f);
        #pragma unroll
        for (int k = 0; k < 3; ++k) {
            const int bk    = (o >> k) & 1;
            const bool flip = ((m ^ mp) >> k) & 1;
            const float2 g  = flip ? (bk ? G[k][3] : G[k][1])
                                   : (bk ? G[k][2] : G[k][0]);
            cf = cmul(cf, g);
        }
        const float2 nv = exch[mp][j];
        res.x += cf.x * nv.x - cf.y * nv.y;
        res.y += cf.x * nv.y + cf.y * nv.x;
    }

    // ---- write red[r, j] ----
    const int e = b * (DA * DA) + r * DA + j;
    if (real_only) {
        out[e] = res.x;                             // complex64 ref coerced to real part
    } else {
        ((float2*)out)[e] = res;                    // interleaved complex64
    }
}

extern "C" void kernel_launch(void* const* d_in, const int* in_sizes, int n_in,
                              void* d_out, int out_size, void* d_ws, size_t ws_size,
                              hipStream_t stream) {
    const float* x = (const float*)d_in[0];   // [2,1,4096] fp32
    const float* w = (const float*)d_in[1];   // [72] fp32
    const int B = in_sizes[0] / DIMQ;         // = 2
    const int real_only = (out_size == B * DA * DA) ? 1 : 0;  // 8192 -> real-only
    quconv_kernel<<<dim3(B * 8), dim3(512), 0, stream>>>(x, w, (float*)d_out, real_only);
}